// Round 7
// baseline (492.188 us; speedup 1.0000x reference)
//
#include <hip/hip_runtime.h>
#include <math.h>

#define DDIM 512
#define NS 96
#define KMASK 0xFFFFF800
#define NEG_INF (-3.0e38f)
#define IMAX 0x7fffffff

typedef _Float16 f16x8 __attribute__((ext_vector_type(8)));
typedef float    f32x4 __attribute__((ext_vector_type(4)));
typedef int      i32x4 __attribute__((ext_vector_type(4)));

__device__ __forceinline__ int imin(int a, int b) { return a < b ? a : b; }
__device__ __forceinline__ int imax(int a, int b) { return a > b ? a : b; }

// exact median-of-3 (VOP3, single instruction) — top-4 insert becomes 1 max + 3 med3
__device__ __forceinline__ int med3(int a, int b, int c) {
    int d;
    asm("v_med3_i32 %0, %1, %2, %3" : "=v"(d) : "v"(a), "v"(b), "v"(c));
    return d;
}

__device__ __forceinline__ void glds16(const void* g, void* l) {
    __builtin_amdgcn_global_load_lds((const __attribute__((address_space(1))) void*)g,
                                     (__attribute__((address_space(3))) void*)l, 16, 0, 0);
}

// Counted-vmcnt barriers (T4: NEVER drain to 0 in the steady loop).
// Wait retires everything except the N newest VMEM ops, then raw barrier.
#define KBAR4() do { asm volatile("s_waitcnt vmcnt(4)" ::: "memory"); \
                     __builtin_amdgcn_s_barrier();                    \
                     asm volatile("" ::: "memory"); } while (0)
#define KBAR8() do { asm volatile("s_waitcnt vmcnt(8)" ::: "memory"); \
                     __builtin_amdgcn_s_barrier();                    \
                     asm volatile("" ::: "memory"); } while (0)

// fp32 rows -> f16 tile + reciprocal norms, single pass.
// TILE LAYOUT (bank-conflict swizzle, verified 0-conflict in R6):
//   slab (ks) = 8192 B = 8 row-groups of 16 rows; within a 1024-B row-group the 64 16-B
//   granules are Q-MAJOR: granule g = q*16 + (row&15). gemm's frag read addr =
//   group*1024 + quad*256 + l16*16 -> dword slot 4*(l16&7): conflict-free ds_read_b128.
// Fused: blocks [0, nbBlocks) process bank, [nbBlocks, ...) process z (one dispatch).
__global__ __launch_bounds__(256) void split_tile_k(
    const float* __restrict__ zsrc, const float* __restrict__ bsrc,
    unsigned* __restrict__ ztile, unsigned* __restrict__ btile,
    float* __restrict__ rz, float* __restrict__ rb,
    int zrows, int brows, int nbBlocks) {

    const int bx = blockIdx.x;
    const float* src; unsigned* tile; float* rn; int rows; int blk;
    if (bx < nbBlocks) { src = bsrc; tile = btile; rn = rb; rows = brows; blk = bx; }
    else               { src = zsrc; tile = ztile; rn = rz; rows = zrows; blk = bx - nbBlocks; }

    const int t = threadIdx.x;
    const int r = t >> 1, hf = t & 1;
    const int R = blk * 128 + r;
    const bool valid = R < rows;
    const float* srow = src + (size_t)(valid ? R : 0) * DDIM + hf * 16;

    float ss = 0.f;
    for (int ks = 0; ks < 16; ++ks) {
        float4 v0 = *(const float4*)(srow + ks * 32);
        float4 v1 = *(const float4*)(srow + ks * 32 + 4);
        float4 v2 = *(const float4*)(srow + ks * 32 + 8);
        float4 v3 = *(const float4*)(srow + ks * 32 + 12);
        ss += v0.x*v0.x + v0.y*v0.y + v0.z*v0.z + v0.w*v0.w
            + v1.x*v1.x + v1.y*v1.y + v1.z*v1.z + v1.w*v1.w
            + v2.x*v2.x + v2.y*v2.y + v2.z*v2.z + v2.w*v2.w
            + v3.x*v3.x + v3.y*v3.y + v3.z*v3.z + v3.w*v3.w;
        unsigned o[8];
        o[0] = __builtin_bit_cast(unsigned, __builtin_amdgcn_cvt_pkrtz(v0.x, v0.y));
        o[1] = __builtin_bit_cast(unsigned, __builtin_amdgcn_cvt_pkrtz(v0.z, v0.w));
        o[2] = __builtin_bit_cast(unsigned, __builtin_amdgcn_cvt_pkrtz(v1.x, v1.y));
        o[3] = __builtin_bit_cast(unsigned, __builtin_amdgcn_cvt_pkrtz(v1.z, v1.w));
        o[4] = __builtin_bit_cast(unsigned, __builtin_amdgcn_cvt_pkrtz(v2.x, v2.y));
        o[5] = __builtin_bit_cast(unsigned, __builtin_amdgcn_cvt_pkrtz(v2.z, v2.w));
        o[6] = __builtin_bit_cast(unsigned, __builtin_amdgcn_cvt_pkrtz(v3.x, v3.y));
        o[7] = __builtin_bit_cast(unsigned, __builtin_amdgcn_cvt_pkrtz(v3.z, v3.w));
        if (!valid) {
            #pragma unroll
            for (int q = 0; q < 8; ++q) o[q] = 0u;   // zero-pad OOB bank rows
        }
        // swizzled store: granules q=2hf and 2hf+1 of row r -> q-major positions
        unsigned* dst = tile + (size_t)(blk * 16 + ks) * 2048
                             + (r >> 4) * 256 + (hf * 32 + (r & 15)) * 4;
        *(i32x4*)dst        = *(i32x4*)o;        // granule 2hf
        *(i32x4*)(dst + 64) = *(i32x4*)(o + 4);  // granule 2hf+1 (+16 granules = +256 B)
    }
    ss += __shfl_xor(ss, 1, 64);
    // rn written for OOB rows too (0.0f): padded-col keys become tag-only, never poisoned.
    if (hf == 0) rn[R] = valid ? 1.0f / fmaxf(sqrtf(ss), 1e-12f) : 0.0f;
}

// f16 screen GEMM (128x128 tile), 3-buffer DEPTH-2 glds pipeline with counted vmcnt:
// stage ks+2 each step, wait vmcnt(4) (allow prev step's batch in flight) -> ~2 steps
// (~500cy) of latency cover per load instead of 1. vmcnt(8) at ks==1 accounts for the
// rbv batch issued in the ks==0 region; waits only ever require batches >=2 regions old,
// so counts are robust to any compiler interleave inside a region. Tail keeps the
// 4-loads-per-step invariant via dummy re-stages. Register-only epilogue (R5/R6 design):
// swapped-operand mfma(bf,af), per-lane top-4 sorted-insert, one cross-quad bitonic
// merge at kernel end. key = (fp32(sim*rb) & KMASK) | iter<<7 | col7.
__global__ __launch_bounds__(256, 3) void gemm_screen_k(
    const unsigned* __restrict__ zh, const unsigned* __restrict__ bh,
    const float* __restrict__ rb,
    int* __restrict__ cand, int N, int nChunks) {

    __shared__ alignas(16) int smem[12288];   // 48 KB: three 16 KB stage buffers

    const int t = threadIdx.x;
    const int w = t >> 6, lane = t & 63;
    const int wz = w >> 1, wb = w & 1;          // z-row block / bank-col block
    const int quad = lane >> 4, l16 = lane & 15;
    const int split = blockIdx.x, rowblk = blockIdx.y;
    const int soff = w * 1024 + lane * 16;

    // per-lane private top-4 per z-row (zi): sorted desc T[zi][0] >= ... >= T[zi][3]
    int T[4][4];
    #pragma unroll
    for (int zi = 0; zi < 4; ++zi)
        #pragma unroll
        for (int q = 0; q < 4; ++q) T[zi][q] = (int)0x80000000;

    // rotating buffer pointers (named, no runtime indexing — rule #20)
    char* pr = (char*)smem;            // buffer read this step
    char* pn = (char*)smem + 16384;    // buffer for next step (staged)
    char* pw = (char*)smem + 32768;    // stage target (step+2)

    // STAGE slab ks=(KK) of chunk (CC) into buffer (DST): 4 glds16 (16 KB)
    #define STAGE(KK, CC, DST) do {                                              \
        const char* gA_ = (const char*)zh + (size_t)(rowblk * 16 + (KK)) * 8192; \
        const char* gB_ = (const char*)bh + (size_t)((CC) * 16 + (KK)) * 8192;   \
        glds16(gA_ + soff,        (DST) + soff);                                 \
        glds16(gA_ + 4096 + soff, (DST) + 4096 + soff);                          \
        glds16(gB_ + soff,        (DST) + 8192 + soff);                          \
        glds16(gB_ + 4096 + soff, (DST) + 12288 + soff);                         \
    } while (0)

    // prologue: stage steps 0 and 1 of the first chunk
    STAGE(0, split, pr);
    STAGE(1, split, pn);

    int iter = 0;
    for (int chunk = split; chunk < nChunks; chunk += NS, ++iter) {
        f32x4 acc[4][4];   // acc[bi][zi]: bank-col frag bi x z-row frag zi
        #pragma unroll
        for (int bi = 0; bi < 4; ++bi)
            #pragma unroll
            for (int zi = 0; zi < 4; ++zi) acc[bi][zi] = (f32x4){0.f, 0.f, 0.f, 0.f};
        f32x4 rbv[4];      // rbv[bi][rr]: col-norm recip for this lane's 16 cols

        #pragma unroll
        for (int ks = 0; ks < 16; ++ks) {
            // wait for buf pr's stage (issued 2 steps ago), allow newer batches in flight
            if (ks == 1) KBAR8(); else KBAR4();

            if (ks == 0) {
                // hoisted col-norm loads, once per chunk (retired by the ks==2 wait;
                // compiler tracks their own use-wait for the epilogue)
                #pragma unroll
                for (int bi = 0; bi < 4; ++bi)
                    rbv[bi] = *(const f32x4*)(rb + chunk * 128 + wb * 64 + bi * 16 + quad * 4);
            }
            // stage step ks+2 into pw (its readers finished before the barrier above)
            {
                int tk = ks + 2, tc = chunk;
                if (tk > 15) { tk -= 16; tc += NS; }
                if (tc >= nChunks) { tk = ks; tc = chunk; }   // dummy: keep 4 loads/step
                STAGE(tk, tc, pw);
            }

            // swizzled frag reads from pr: group*1024 + quad*256 + l16*16 (conflict-free)
            f16x8 af[4], bf[4];
            #pragma unroll
            for (int zi = 0; zi < 4; ++zi)
                af[zi] = __builtin_bit_cast(f16x8,
                    *(const i32x4*)(pr + (wz * 4 + zi) * 1024 + quad * 256 + l16 * 16));
            #pragma unroll
            for (int bi = 0; bi < 4; ++bi)
                bf[bi] = __builtin_bit_cast(f16x8,
                    *(const i32x4*)(pr + 8192 + (wb * 4 + bi) * 1024 + quad * 256 + l16 * 16));
            // swapped operands: out col(l16) = z-row, out row(quad*4+rr) = bank-col
            #pragma unroll
            for (int bi = 0; bi < 4; ++bi)
                #pragma unroll
                for (int zi = 0; zi < 4; ++zi)
                    acc[bi][zi] = __builtin_amdgcn_mfma_f32_16x16x32_f16(bf[bi], af[zi], acc[bi][zi], 0, 0, 0);

            // rotate buffers
            char* tp = pr; pr = pn; pn = pw; pw = tp;
        }

        // register-only epilogue: sorted-insert this lane's 16 cols per z-row.
        // col = wb*64 + bi*16 + quad*4 + rr  (7 bits, no carry into iter field)
        const int tbase = (iter << 7) | (wb << 6) | (quad << 2);
        #pragma unroll
        for (int zi = 0; zi < 4; ++zi)
            #pragma unroll
            for (int bi = 0; bi < 4; ++bi)
                #pragma unroll
                for (int rr = 0; rr < 4; ++rr) {
                    float v = acc[bi][zi][rr] * rbv[bi][rr];
                    int kk = (__float_as_int(v) & KMASK) | (tbase + bi * 16 + rr);
                    int n1 = med3(kk, T[zi][0], T[zi][1]);
                    int n2 = med3(kk, T[zi][1], T[zi][2]);
                    int n3 = med3(kk, T[zi][2], T[zi][3]);
                    T[zi][0] = imax(kk, T[zi][0]);
                    T[zi][1] = n1; T[zi][2] = n2; T[zi][3] = n3;
                }
    }
    #undef STAGE

    // final cross-quad merge: lanes {l16, l16+16, l16+32, l16+48} hold disjoint col sets
    // for the same z-rows. Bitonic top-4 merge of sorted-desc lists via shfl_xor(16,32).
    #pragma unroll
    for (int zi = 0; zi < 4; ++zi) {
        int a0 = T[zi][0], a1 = T[zi][1], a2 = T[zi][2], a3 = T[zi][3];
        #pragma unroll
        for (int off = 16; off <= 32; off <<= 1) {
            int p0 = __shfl_xor(a0, off, 64);
            int p1 = __shfl_xor(a1, off, 64);
            int p2 = __shfl_xor(a2, off, 64);
            int p3 = __shfl_xor(a3, off, 64);
            int m0 = imax(a0, p3), m1 = imax(a1, p2), m2 = imax(a2, p1), m3 = imax(a3, p0);
            int b0 = imax(m0, m2), b2 = imin(m0, m2), b1 = imax(m1, m3), b3 = imin(m1, m3);
            a0 = imax(b0, b1); a1 = imin(b0, b1); a2 = imax(b2, b3); a3 = imin(b2, b3);
        }
        if (quad == 0) {
            i32x4 outk = { a0, a1, a2, a3 };
            const int row = rowblk * 128 + wz * 64 + zi * 16 + l16;
            *(i32x4*)(cand + (((size_t)row * NS + split) * 2 + wb) * 4) = outk;
        }
    }
}

// per row: pop exact top-32 of 768 packed keys, exact fp32 rescore, final top-5
__global__ __launch_bounds__(256) void merge_rescore_k(
    const int* __restrict__ cand,
    const float* __restrict__ z, const float* __restrict__ bank,
    const float* __restrict__ rz, const float* __restrict__ rb,
    const int* __restrict__ labels, float* __restrict__ out, int BK, int N) {

    __shared__ float zrow[DDIM];
    __shared__ int   idxs[32];
    __shared__ float dots[32];

    const int row = blockIdx.x;
    const int t = threadIdx.x, w = t >> 6, lane = t & 63;

    {   float2 v = *(const float2*)(z + (size_t)row * DDIM + t * 2);
        zrow[t * 2] = v.x; zrow[t * 2 + 1] = v.y; }

    if (w == 0) {
        int k[12];
        const int* cp = cand + (size_t)row * (NS * 2 * 4) + lane * 12;
        #pragma unroll
        for (int q = 0; q < 12; ++q) k[q] = cp[q];
        for (int r = 0; r < 32; ++r) {
            int lk = k[0], lq = 0;
            #pragma unroll
            for (int q = 1; q < 12; ++q) if (k[q] > lk) { lk = k[q]; lq = q; }
            int wk = lk, wl = lane, wq = lq;
            #pragma unroll
            for (int off = 32; off > 0; off >>= 1) {
                int ok = __shfl_xor(wk, off, 64);
                int ol = __shfl_xor(wl, off, 64);
                int oq = __shfl_xor(wq, off, 64);
                if (ok > wk || (ok == wk && ol < wl)) { wk = ok; wl = ol; wq = oq; }
            }
            if (lane == wl) {
                #pragma unroll
                for (int q = 0; q < 12; ++q) if (q == wq) k[q] = (int)0x80000000;
            }
            if (lane == 0) {
                int j = wl * 12 + wq;         // position -> (split, h, slot)
                int split = j >> 3;
                int c = wk & 127, it = (wk >> 7) & 15;
                int gi = (it * NS + split) * 128 + c;
                idxs[r] = gi < N ? gi : 0;    // statistically impossible, fault-guard only
            }
        }
    }
    __syncthreads();

    // exact fp32 raw dot for the 32 survivors: wave w handles w*8..w*8+7
    #pragma unroll
    for (int jj = 0; jj < 8; ++jj) {
        const int ci = idxs[w * 8 + jj];
        const float* br = bank + (size_t)ci * DDIM + lane * 8;
        float4 x0 = *(const float4*)br;
        float4 x1 = *(const float4*)(br + 4);
        const float* zz = zrow + lane * 8;
        float4 z0 = *(const float4*)zz;
        float4 z1 = *(const float4*)(zz + 4);
        float s = x0.x*z0.x + x0.y*z0.y + x0.z*z0.z + x0.w*z0.w
                + x1.x*z1.x + x1.y*z1.y + x1.z*z1.z + x1.w*z1.w;
        #pragma unroll
        for (int off = 32; off > 0; off >>= 1) s += __shfl_xor(s, off, 64);
        if (lane == 0) dots[w * 8 + jj] = s;
    }
    __syncthreads();

    if (w == 0) {
        const float rzv = rz[row];
        float v; int ii;
        if (lane < 32) { ii = idxs[lane]; v = dots[lane] * rzv * rb[ii]; }
        else           { ii = IMAX;       v = NEG_INF; }
        for (int r = 0; r < 5; ++r) {
            float bv = v; int bi = ii;
            #pragma unroll
            for (int off = 32; off > 0; off >>= 1) {
                float ov = __shfl_xor(bv, off, 64);
                int   oi = __shfl_xor(bi, off, 64);
                if (ov > bv || (ov == bv && oi < bi)) { bv = ov; bi = oi; }
            }
            if (v == bv && ii == bi) { v = NEG_INF; ii = IMAX; }
            if (lane == 0) {
                out[(size_t)row * 5 + r]          = (float)bi;
                out[BK + (size_t)row * 5 + r]     = bv;
                out[2 * BK + (size_t)row * 5 + r] = (float)labels[bi];
            }
        }
    }
}

extern "C" void kernel_launch(void* const* d_in, const int* in_sizes, int n_in,
                              void* d_out, int out_size, void* d_ws, size_t ws_size,
                              hipStream_t stream) {
    const float* z    = (const float*)d_in[0];
    const float* bank = (const float*)d_in[1];
    const int*   lab  = (const int*)d_in[2];
    const int B = in_sizes[0] / DDIM;     // 1024
    const int N = in_sizes[1] / DDIM;     // 100000
    const int BK = out_size / 3;          // 5120
    const int nChunks = (N + 127) >> 7;   // 782
    float* out = (float*)d_out;
    char* ws = (char*)d_ws;

    const size_t o_rz = 0;                                       // B floats (pad 4K)
    const size_t o_rb = 4096;                                    // nChunks*128 floats
    const size_t o_zh = o_rb + (size_t)nChunks * 128 * 4;        // z f16 tile (1 MB)
    const size_t o_bh = o_zh + (size_t)(B / 128) * 16 * 8192;    // bank f16 tile (102.5 MB)
    const size_t o_cv = o_bh + (size_t)nChunks * 16 * 8192;      // cand keys (3 MB)

    float* rz = (float*)(ws + o_rz);
    float* rb = (float*)(ws + o_rb);
    unsigned* zh = (unsigned*)(ws + o_zh);
    unsigned* bh = (unsigned*)(ws + o_bh);
    int* cand = (int*)(ws + o_cv);

    split_tile_k<<<nChunks + B / 128, 256, 0, stream>>>(z, bank, zh, bh, rz, rb, B, N, nChunks);
    gemm_screen_k<<<dim3(NS, B / 128), 256, 0, stream>>>(zh, bh, rb, cand, N, nChunks);
    merge_rescore_k<<<B, 256, 0, stream>>>(cand, z, bank, rz, rb, lab, out, BK, N);
}

// Round 8
// 481.966 us; speedup vs baseline: 1.0212x; 1.0212x over previous
//
#include <hip/hip_runtime.h>
#include <math.h>

#define DDIM 512
#define NS 96
#define KMASK 0xFFFFF800
#define NEG_INF (-3.0e38f)
#define IMAX 0x7fffffff

typedef _Float16 f16x8 __attribute__((ext_vector_type(8)));
typedef float    f32x4 __attribute__((ext_vector_type(4)));
typedef int      i32x4 __attribute__((ext_vector_type(4)));

__device__ __forceinline__ int imin(int a, int b) { return a < b ? a : b; }
__device__ __forceinline__ int imax(int a, int b) { return a > b ? a : b; }

// exact median-of-3 (VOP3, single instruction) — top-4 insert becomes 1 max + 3 med3
__device__ __forceinline__ int med3(int a, int b, int c) {
    int d;
    asm("v_med3_i32 %0, %1, %2, %3" : "=v"(d) : "v"(a), "v"(b), "v"(c));
    return d;
}

__device__ __forceinline__ void glds16(const void* g, void* l) {
    __builtin_amdgcn_global_load_lds((const __attribute__((address_space(1))) void*)g,
                                     (__attribute__((address_space(3))) void*)l, 16, 0, 0);
}

// non-temporal 16-B load: streams the fp32 inputs PAST L2/L3 (nt policy) so split's
// 205-MB bank read doesn't evict the f16 tile lines gemm needs L3-resident.
__device__ __forceinline__ f32x4 nt4(const float* p) {
    return __builtin_nontemporal_load((const f32x4*)p);
}

// K-loop barrier: wait own staging loads (issued one full iteration ago -> latency hidden),
// then raw barrier. NO lgkm drain -> prefetch pipelining survives.
#define KBAR() do { asm volatile("s_waitcnt vmcnt(0)" ::: "memory"); \
                    __builtin_amdgcn_s_barrier();                    \
                    asm volatile("" ::: "memory"); } while (0)

// fp32 rows -> f16 tile + reciprocal norms, single pass, NT source reads.
// TILE LAYOUT (bank-conflict swizzle, verified 0-conflict in R6):
//   slab (ks) = 8192 B = 8 row-groups of 16 rows; within a 1024-B row-group the 64 16-B
//   granules are Q-MAJOR: granule g = q*16 + (row&15). gemm's frag read addr =
//   group*1024 + quad*256 + l16*16 -> dword slot 4*(l16&7): conflict-free ds_read_b128.
// Fused: blocks [0, nbBlocks) process bank, [nbBlocks, ...) process z (one dispatch).
__global__ __launch_bounds__(256) void split_tile_k(
    const float* __restrict__ zsrc, const float* __restrict__ bsrc,
    unsigned* __restrict__ ztile, unsigned* __restrict__ btile,
    float* __restrict__ rz, float* __restrict__ rb,
    int zrows, int brows, int nbBlocks) {

    const int bx = blockIdx.x;
    const float* src; unsigned* tile; float* rn; int rows; int blk;
    if (bx < nbBlocks) { src = bsrc; tile = btile; rn = rb; rows = brows; blk = bx; }
    else               { src = zsrc; tile = ztile; rn = rz; rows = zrows; blk = bx - nbBlocks; }

    const int t = threadIdx.x;
    const int r = t >> 1, hf = t & 1;
    const int R = blk * 128 + r;
    const bool valid = R < rows;
    const float* srow = src + (size_t)(valid ? R : 0) * DDIM + hf * 16;

    float ss = 0.f;
    for (int ks = 0; ks < 16; ++ks) {
        f32x4 v0 = nt4(srow + ks * 32);
        f32x4 v1 = nt4(srow + ks * 32 + 4);
        f32x4 v2 = nt4(srow + ks * 32 + 8);
        f32x4 v3 = nt4(srow + ks * 32 + 12);
        ss += v0[0]*v0[0] + v0[1]*v0[1] + v0[2]*v0[2] + v0[3]*v0[3]
            + v1[0]*v1[0] + v1[1]*v1[1] + v1[2]*v1[2] + v1[3]*v1[3]
            + v2[0]*v2[0] + v2[1]*v2[1] + v2[2]*v2[2] + v2[3]*v2[3]
            + v3[0]*v3[0] + v3[1]*v3[1] + v3[2]*v3[2] + v3[3]*v3[3];
        unsigned o[8];
        o[0] = __builtin_bit_cast(unsigned, __builtin_amdgcn_cvt_pkrtz(v0[0], v0[1]));
        o[1] = __builtin_bit_cast(unsigned, __builtin_amdgcn_cvt_pkrtz(v0[2], v0[3]));
        o[2] = __builtin_bit_cast(unsigned, __builtin_amdgcn_cvt_pkrtz(v1[0], v1[1]));
        o[3] = __builtin_bit_cast(unsigned, __builtin_amdgcn_cvt_pkrtz(v1[2], v1[3]));
        o[4] = __builtin_bit_cast(unsigned, __builtin_amdgcn_cvt_pkrtz(v2[0], v2[1]));
        o[5] = __builtin_bit_cast(unsigned, __builtin_amdgcn_cvt_pkrtz(v2[2], v2[3]));
        o[6] = __builtin_bit_cast(unsigned, __builtin_amdgcn_cvt_pkrtz(v3[0], v3[1]));
        o[7] = __builtin_bit_cast(unsigned, __builtin_amdgcn_cvt_pkrtz(v3[2], v3[3]));
        if (!valid) {
            #pragma unroll
            for (int q = 0; q < 8; ++q) o[q] = 0u;   // zero-pad OOB bank rows
        }
        // swizzled store: granules q=2hf and 2hf+1 of row r -> q-major positions
        unsigned* dst = tile + (size_t)(blk * 16 + ks) * 2048
                             + (r >> 4) * 256 + (hf * 32 + (r & 15)) * 4;
        *(i32x4*)dst        = *(i32x4*)o;        // granule 2hf
        *(i32x4*)(dst + 64) = *(i32x4*)(o + 4);  // granule 2hf+1 (+16 granules = +256 B)
    }
    ss += __shfl_xor(ss, 1, 64);
    // rn written for OOB rows too (0.0f): padded-col keys become tag-only, never poisoned.
    if (hf == 0) rn[R] = valid ? 1.0f / fmaxf(sqrtf(ss), 1e-12f) : 0.0f;
}

// f16 screen GEMM (128x128 tile), 2-phase double-buffered glds staging with counted
// vmcnt + raw barriers, cross-chunk ks=0 prefetch into buf0 during the epilogue.
// (R6 structure verbatim — R7's depth-2 variant doubled FETCH via block drift, reverted.)
// SWAPPED-OPERAND epilogue: mfma(bf, af) puts 16 bank-cols x 4 z-rows in each lane's
// registers -> per-row top-4 is a private in-register sorted-insert (1 max + 3 med3),
// carried across chunks per-lane, merged across quads once at kernel end via
// bitonic shfl_xor(16,32). key = (fp32(sim*rb) & KMASK) | iter<<7 | col7.
__global__ __launch_bounds__(256, 4) void gemm_screen_k(
    const unsigned* __restrict__ zh, const unsigned* __restrict__ bh,
    const float* __restrict__ rb,
    int* __restrict__ cand, int N, int nChunks) {

    __shared__ alignas(16) int smem[8192];   // 32 KB: two 16 KB stage buffers

    const int t = threadIdx.x;
    const int w = t >> 6, lane = t & 63;
    const int wz = w >> 1, wb = w & 1;          // z-row block / bank-col block
    const int quad = lane >> 4, l16 = lane & 15;
    const int split = blockIdx.x, rowblk = blockIdx.y;
    const int soff = w * 1024 + lane * 16;

    // per-lane private top-4 per z-row (zi): sorted desc T[zi][0] >= ... >= T[zi][3]
    int T[4][4];
    #pragma unroll
    for (int zi = 0; zi < 4; ++zi)
        #pragma unroll
        for (int q = 0; q < 4; ++q) T[zi][q] = (int)0x80000000;

    // prologue: stage ks=0 of first chunk into buf0
    {
        const char* gA = (const char*)zh + (size_t)(rowblk * 16) * 8192;
        const char* gB = (const char*)bh + (size_t)(split * 16) * 8192;
        glds16(gA + soff,        (char*)smem + soff);
        glds16(gA + 4096 + soff, (char*)smem + 4096 + soff);
        glds16(gB + soff,        (char*)smem + 8192 + soff);
        glds16(gB + 4096 + soff, (char*)smem + 12288 + soff);
    }

    int iter = 0;
    for (int chunk = split; chunk < nChunks; chunk += NS, ++iter) {
        f32x4 acc[4][4];   // acc[bi][zi]: bank-col frag bi x z-row frag zi
        #pragma unroll
        for (int bi = 0; bi < 4; ++bi)
            #pragma unroll
            for (int zi = 0; zi < 4; ++zi) acc[bi][zi] = (f32x4){0.f, 0.f, 0.f, 0.f};
        f32x4 rbv[4];      // rbv[bi][rr]: col-norm recip for this lane's 16 cols

        #pragma unroll 2
        for (int ks = 0; ks < 16; ++ks) {
            // buf[ks&1] fully staged once all waves pass this barrier (each drained its own
            // glds via vmcnt(0); those loads were issued a full iteration ago).
            KBAR();
            if (ks < 15) {
                const char* gA = (const char*)zh + (size_t)(rowblk * 16 + ks + 1) * 8192;
                const char* gB = (const char*)bh + (size_t)(chunk * 16 + ks + 1) * 8192;
                char* l = (char*)smem + (((ks & 1) ^ 1) << 14);
                glds16(gA + soff,        l + soff);
                glds16(gA + 4096 + soff, l + 4096 + soff);
                glds16(gB + soff,        l + 8192 + soff);
                glds16(gB + 4096 + soff, l + 12288 + soff);
            } else if (chunk + NS < nChunks) {
                // cross-chunk prefetch: ks=0 of next chunk into buf0; lands during the
                // epilogue, consumed at next chunk's ks=0 KBAR.
                const char* gA = (const char*)zh + (size_t)(rowblk * 16) * 8192;
                const char* gB = (const char*)bh + (size_t)((chunk + NS) * 16) * 8192;
                glds16(gA + soff,        (char*)smem + soff);
                glds16(gA + 4096 + soff, (char*)smem + 4096 + soff);
                glds16(gB + soff,        (char*)smem + 8192 + soff);
                glds16(gB + 4096 + soff, (char*)smem + 12288 + soff);
            }
            if (ks == 0) {
                // hoisted col-norm loads (lane-uniform across l16, consumed in epilogue)
                #pragma unroll
                for (int bi = 0; bi < 4; ++bi)
                    rbv[bi] = *(const f32x4*)(rb + chunk * 128 + wb * 64 + bi * 16 + quad * 4);
            }

            // swizzled frag reads: group*1024 + quad*256 + l16*16 (conflict-free)
            const char* Ab = (const char*)smem + ((ks & 1) << 14);
            const char* Bb = Ab + 8192;
            f16x8 af[4], bf[4];
            #pragma unroll
            for (int zi = 0; zi < 4; ++zi)
                af[zi] = __builtin_bit_cast(f16x8,
                    *(const i32x4*)(Ab + (wz * 4 + zi) * 1024 + quad * 256 + l16 * 16));
            #pragma unroll
            for (int bi = 0; bi < 4; ++bi)
                bf[bi] = __builtin_bit_cast(f16x8,
                    *(const i32x4*)(Bb + (wb * 4 + bi) * 1024 + quad * 256 + l16 * 16));
            // swapped operands: out col(l16) = z-row, out row(quad*4+rr) = bank-col
            #pragma unroll
            for (int bi = 0; bi < 4; ++bi)
                #pragma unroll
                for (int zi = 0; zi < 4; ++zi)
                    acc[bi][zi] = __builtin_amdgcn_mfma_f32_16x16x32_f16(bf[bi], af[zi], acc[bi][zi], 0, 0, 0);
        }

        // epilogue: pure-register sorted-insert of this lane's 16 cols per z-row.
        // col = wb*64 + bi*16 + quad*4 + rr  (7 bits, no carry into iter field)
        const int tbase = (iter << 7) | (wb << 6) | (quad << 2);
        #pragma unroll
        for (int zi = 0; zi < 4; ++zi)
            #pragma unroll
            for (int bi = 0; bi < 4; ++bi)
                #pragma unroll
                for (int rr = 0; rr < 4; ++rr) {
                    float v = acc[bi][zi][rr] * rbv[bi][rr];
                    int kk = (__float_as_int(v) & KMASK) | (tbase + bi * 16 + rr);
                    int n1 = med3(kk, T[zi][0], T[zi][1]);
                    int n2 = med3(kk, T[zi][1], T[zi][2]);
                    int n3 = med3(kk, T[zi][2], T[zi][3]);
                    T[zi][0] = imax(kk, T[zi][0]);
                    T[zi][1] = n1; T[zi][2] = n2; T[zi][3] = n3;
                }
    }

    // final cross-quad merge: lanes {l16, l16+16, l16+32, l16+48} hold disjoint col sets
    // for the same z-rows. Bitonic top-4 merge of sorted-desc lists via shfl_xor(16,32).
    #pragma unroll
    for (int zi = 0; zi < 4; ++zi) {
        int a0 = T[zi][0], a1 = T[zi][1], a2 = T[zi][2], a3 = T[zi][3];
        #pragma unroll
        for (int off = 16; off <= 32; off <<= 1) {
            int p0 = __shfl_xor(a0, off, 64);
            int p1 = __shfl_xor(a1, off, 64);
            int p2 = __shfl_xor(a2, off, 64);
            int p3 = __shfl_xor(a3, off, 64);
            int m0 = imax(a0, p3), m1 = imax(a1, p2), m2 = imax(a2, p1), m3 = imax(a3, p0);
            int b0 = imax(m0, m2), b2 = imin(m0, m2), b1 = imax(m1, m3), b3 = imin(m1, m3);
            a0 = imax(b0, b1); a1 = imin(b0, b1); a2 = imax(b2, b3); a3 = imin(b2, b3);
        }
        if (quad == 0) {
            i32x4 outk = { a0, a1, a2, a3 };
            const int row = rowblk * 128 + wz * 64 + zi * 16 + l16;
            *(i32x4*)(cand + (((size_t)row * NS + split) * 2 + wb) * 4) = outk;
        }
    }
}

// per row: pop exact top-32 of 768 packed keys, exact fp32 rescore, final top-5
__global__ __launch_bounds__(256) void merge_rescore_k(
    const int* __restrict__ cand,
    const float* __restrict__ z, const float* __restrict__ bank,
    const float* __restrict__ rz, const float* __restrict__ rb,
    const int* __restrict__ labels, float* __restrict__ out, int BK, int N) {

    __shared__ float zrow[DDIM];
    __shared__ int   idxs[32];
    __shared__ float dots[32];

    const int row = blockIdx.x;
    const int t = threadIdx.x, w = t >> 6, lane = t & 63;

    {   float2 v = *(const float2*)(z + (size_t)row * DDIM + t * 2);
        zrow[t * 2] = v.x; zrow[t * 2 + 1] = v.y; }

    if (w == 0) {
        int k[12];
        const int* cp = cand + (size_t)row * (NS * 2 * 4) + lane * 12;
        #pragma unroll
        for (int q = 0; q < 12; ++q) k[q] = cp[q];
        for (int r = 0; r < 32; ++r) {
            int lk = k[0], lq = 0;
            #pragma unroll
            for (int q = 1; q < 12; ++q) if (k[q] > lk) { lk = k[q]; lq = q; }
            int wk = lk, wl = lane, wq = lq;
            #pragma unroll
            for (int off = 32; off > 0; off >>= 1) {
                int ok = __shfl_xor(wk, off, 64);
                int ol = __shfl_xor(wl, off, 64);
                int oq = __shfl_xor(wq, off, 64);
                if (ok > wk || (ok == wk && ol < wl)) { wk = ok; wl = ol; wq = oq; }
            }
            if (lane == wl) {
                #pragma unroll
                for (int q = 0; q < 12; ++q) if (q == wq) k[q] = (int)0x80000000;
            }
            if (lane == 0) {
                int j = wl * 12 + wq;         // position -> (split, h, slot)
                int split = j >> 3;
                int c = wk & 127, it = (wk >> 7) & 15;
                int gi = (it * NS + split) * 128 + c;
                idxs[r] = gi < N ? gi : 0;    // statistically impossible, fault-guard only
            }
        }
    }
    __syncthreads();

    // exact fp32 raw dot for the 32 survivors: wave w handles w*8..w*8+7
    #pragma unroll
    for (int jj = 0; jj < 8; ++jj) {
        const int ci = idxs[w * 8 + jj];
        const float* br = bank + (size_t)ci * DDIM + lane * 8;
        float4 x0 = *(const float4*)br;
        float4 x1 = *(const float4*)(br + 4);
        const float* zz = zrow + lane * 8;
        float4 z0 = *(const float4*)zz;
        float4 z1 = *(const float4*)(zz + 4);
        float s = x0.x*z0.x + x0.y*z0.y + x0.z*z0.z + x0.w*z0.w
                + x1.x*z1.x + x1.y*z1.y + x1.z*z1.z + x1.w*z1.w;
        #pragma unroll
        for (int off = 32; off > 0; off >>= 1) s += __shfl_xor(s, off, 64);
        if (lane == 0) dots[w * 8 + jj] = s;
    }
    __syncthreads();

    if (w == 0) {
        const float rzv = rz[row];
        float v; int ii;
        if (lane < 32) { ii = idxs[lane]; v = dots[lane] * rzv * rb[ii]; }
        else           { ii = IMAX;       v = NEG_INF; }
        for (int r = 0; r < 5; ++r) {
            float bv = v; int bi = ii;
            #pragma unroll
            for (int off = 32; off > 0; off >>= 1) {
                float ov = __shfl_xor(bv, off, 64);
                int   oi = __shfl_xor(bi, off, 64);
                if (ov > bv || (ov == bv && oi < bi)) { bv = ov; bi = oi; }
            }
            if (v == bv && ii == bi) { v = NEG_INF; ii = IMAX; }
            if (lane == 0) {
                out[(size_t)row * 5 + r]          = (float)bi;
                out[BK + (size_t)row * 5 + r]     = bv;
                out[2 * BK + (size_t)row * 5 + r] = (float)labels[bi];
            }
        }
    }
}

extern "C" void kernel_launch(void* const* d_in, const int* in_sizes, int n_in,
                              void* d_out, int out_size, void* d_ws, size_t ws_size,
                              hipStream_t stream) {
    const float* z    = (const float*)d_in[0];
    const float* bank = (const float*)d_in[1];
    const int*   lab  = (const int*)d_in[2];
    const int B = in_sizes[0] / DDIM;     // 1024
    const int N = in_sizes[1] / DDIM;     // 100000
    const int BK = out_size / 3;          // 5120
    const int nChunks = (N + 127) >> 7;   // 782
    float* out = (float*)d_out;
    char* ws = (char*)d_ws;

    const size_t o_rz = 0;                                       // B floats (pad 4K)
    const size_t o_rb = 4096;                                    // nChunks*128 floats
    const size_t o_zh = o_rb + (size_t)nChunks * 128 * 4;        // z f16 tile (1 MB)
    const size_t o_bh = o_zh + (size_t)(B / 128) * 16 * 8192;    // bank f16 tile (102.5 MB)
    const size_t o_cv = o_bh + (size_t)nChunks * 16 * 8192;      // cand keys (3 MB)

    float* rz = (float*)(ws + o_rz);
    float* rb = (float*)(ws + o_rb);
    unsigned* zh = (unsigned*)(ws + o_zh);
    unsigned* bh = (unsigned*)(ws + o_bh);
    int* cand = (int*)(ws + o_cv);

    split_tile_k<<<nChunks + B / 128, 256, 0, stream>>>(z, bank, zh, bh, rz, rb, B, N, nChunks);
    gemm_screen_k<<<dim3(NS, B / 128), 256, 0, stream>>>(zh, bh, rb, cand, N, nChunks);
    merge_rescore_k<<<B, 256, 0, stream>>>(cand, z, bank, rz, rb, lab, out, BK, N);
}

// Round 9
// 466.222 us; speedup vs baseline: 1.0557x; 1.0338x over previous
//
#include <hip/hip_runtime.h>
#include <math.h>

#define DDIM 512
#define NS 96
#define KMASK 0xFFFFF800
#define NEG_INF (-3.0e38f)
#define IMAX 0x7fffffff

typedef _Float16 f16x8 __attribute__((ext_vector_type(8)));
typedef float    f32x4 __attribute__((ext_vector_type(4)));
typedef int      i32x4 __attribute__((ext_vector_type(4)));

__device__ __forceinline__ int imin(int a, int b) { return a < b ? a : b; }
__device__ __forceinline__ int imax(int a, int b) { return a > b ? a : b; }

// exact median-of-3 (VOP3, single instruction) — top-4 insert becomes 1 max + 3 med3
__device__ __forceinline__ int med3(int a, int b, int c) {
    int d;
    asm("v_med3_i32 %0, %1, %2, %3" : "=v"(d) : "v"(a), "v"(b), "v"(c));
    return d;
}

__device__ __forceinline__ void glds16(const void* g, void* l) {
    __builtin_amdgcn_global_load_lds((const __attribute__((address_space(1))) void*)g,
                                     (__attribute__((address_space(3))) void*)l, 16, 0, 0);
}

// K-loop barrier: wait own staging loads (issued one full iteration ago -> latency hidden),
// then raw barrier. vmcnt(0) keeps the 8 rowblk-blocks sharing a split's B slabs in
// lockstep (R7 showed counted-vmcnt decoupling doubles HBM FETCH via block drift).
#define KBAR() do { asm volatile("s_waitcnt vmcnt(0)" ::: "memory"); \
                    __builtin_amdgcn_s_barrier();                    \
                    asm volatile("" ::: "memory"); } while (0)

// fp32 rows -> f16 tile + reciprocal norms, single pass (R6 version, NT reverted: R8
// showed nt loads cost split ~+19us for no gemm gain).
// TILE LAYOUT (bank-conflict swizzle, verified 0-conflict in R6):
//   slab (ks) = 8192 B = 8 row-groups of 16 rows; within a 1024-B row-group the 64 16-B
//   granules are Q-MAJOR: granule g = q*16 + (row&15). gemm's frag read addr =
//   group*1024 + quad*256 + l16*16 -> dword slot 4*(l16&7): conflict-free ds_read_b128.
// Fused: blocks [0, nbBlocks) process bank, [nbBlocks, ...) process z (one dispatch).
__global__ __launch_bounds__(256) void split_tile_k(
    const float* __restrict__ zsrc, const float* __restrict__ bsrc,
    unsigned* __restrict__ ztile, unsigned* __restrict__ btile,
    float* __restrict__ rz, float* __restrict__ rb,
    int zrows, int brows, int nbBlocks) {

    const int bx = blockIdx.x;
    const float* src; unsigned* tile; float* rn; int rows; int blk;
    if (bx < nbBlocks) { src = bsrc; tile = btile; rn = rb; rows = brows; blk = bx; }
    else               { src = zsrc; tile = ztile; rn = rz; rows = zrows; blk = bx - nbBlocks; }

    const int t = threadIdx.x;
    const int r = t >> 1, hf = t & 1;
    const int R = blk * 128 + r;
    const bool valid = R < rows;
    const float* srow = src + (size_t)(valid ? R : 0) * DDIM + hf * 16;

    float ss = 0.f;
    for (int ks = 0; ks < 16; ++ks) {
        float4 v0 = *(const float4*)(srow + ks * 32);
        float4 v1 = *(const float4*)(srow + ks * 32 + 4);
        float4 v2 = *(const float4*)(srow + ks * 32 + 8);
        float4 v3 = *(const float4*)(srow + ks * 32 + 12);
        ss += v0.x*v0.x + v0.y*v0.y + v0.z*v0.z + v0.w*v0.w
            + v1.x*v1.x + v1.y*v1.y + v1.z*v1.z + v1.w*v1.w
            + v2.x*v2.x + v2.y*v2.y + v2.z*v2.z + v2.w*v2.w
            + v3.x*v3.x + v3.y*v3.y + v3.z*v3.z + v3.w*v3.w;
        unsigned o[8];
        o[0] = __builtin_bit_cast(unsigned, __builtin_amdgcn_cvt_pkrtz(v0.x, v0.y));
        o[1] = __builtin_bit_cast(unsigned, __builtin_amdgcn_cvt_pkrtz(v0.z, v0.w));
        o[2] = __builtin_bit_cast(unsigned, __builtin_amdgcn_cvt_pkrtz(v1.x, v1.y));
        o[3] = __builtin_bit_cast(unsigned, __builtin_amdgcn_cvt_pkrtz(v1.z, v1.w));
        o[4] = __builtin_bit_cast(unsigned, __builtin_amdgcn_cvt_pkrtz(v2.x, v2.y));
        o[5] = __builtin_bit_cast(unsigned, __builtin_amdgcn_cvt_pkrtz(v2.z, v2.w));
        o[6] = __builtin_bit_cast(unsigned, __builtin_amdgcn_cvt_pkrtz(v3.x, v3.y));
        o[7] = __builtin_bit_cast(unsigned, __builtin_amdgcn_cvt_pkrtz(v3.z, v3.w));
        if (!valid) {
            #pragma unroll
            for (int q = 0; q < 8; ++q) o[q] = 0u;   // zero-pad OOB bank rows
        }
        // swizzled store: granules q=2hf and 2hf+1 of row r -> q-major positions
        unsigned* dst = tile + (size_t)(blk * 16 + ks) * 2048
                             + (r >> 4) * 256 + (hf * 32 + (r & 15)) * 4;
        *(i32x4*)dst        = *(i32x4*)o;        // granule 2hf
        *(i32x4*)(dst + 64) = *(i32x4*)(o + 4);  // granule 2hf+1 (+16 granules = +256 B)
    }
    ss += __shfl_xor(ss, 1, 64);
    // rn written for OOB rows too (0.0f): padded-col keys become tag-only, never poisoned.
    if (hf == 0) rn[R] = valid ? 1.0f / fmaxf(sqrtf(ss), 1e-12f) : 0.0f;
}

// f16 screen GEMM (128x128 tile). B-ONLY LDS staging: the z-tile (A) is 1 MB and
// permanently L2/L3-hot, so A fragments are read DIRECTLY from global (same swizzled
// granule addressing on the global pointer; L1 dedups the wz-pair reuse). This halves
// per-step LDS traffic (48KB -> 24KB) — the pipe the R8 cycle-count showed dominant
// (~64% of the per-CU budget). B staged 8KB/step, 2x8KB double-buffer, vmcnt(0)
// lockstep barrier (R7: counted vmcnt decouples blocks -> FETCH doubles), cross-chunk
// B-slab-0 prefetch during the register-only epilogue.
// SWAPPED-OPERAND epilogue: mfma(bf, af) puts 16 bank-cols x 4 z-rows in each lane's
// registers -> per-row top-4 is a private in-register sorted-insert (1 max + 3 med3),
// carried across chunks per-lane, merged across quads once at kernel end via
// bitonic shfl_xor(16,32). key = (fp32(sim*rb) & KMASK) | iter<<7 | col7.
__global__ __launch_bounds__(256, 3) void gemm_screen_k(
    const unsigned* __restrict__ zh, const unsigned* __restrict__ bh,
    const float* __restrict__ rb,
    int* __restrict__ cand, int N, int nChunks) {

    __shared__ alignas(16) int smem[4096];   // 16 KB: two 8 KB B-stage buffers

    const int t = threadIdx.x;
    const int w = t >> 6, lane = t & 63;
    const int wz = w >> 1, wb = w & 1;          // z-row block / bank-col block
    const int quad = lane >> 4, l16 = lane & 15;
    const int split = blockIdx.x, rowblk = blockIdx.y;
    const int soff = t * 16;                    // = w*1024 + lane*16 (wave-uniform + lane*16)

    // per-lane private top-4 per z-row (zi): sorted desc T[zi][0] >= ... >= T[zi][3]
    int T[4][4];
    #pragma unroll
    for (int zi = 0; zi < 4; ++zi)
        #pragma unroll
        for (int q = 0; q < 4; ++q) T[zi][q] = (int)0x80000000;

    // stage B slab (8 KB) of slabIdx into LDS buffer dst
    #define STAGE_B(SLAB, DST) do {                                        \
        const char* gB_ = (const char*)bh + (size_t)(SLAB) * 8192;         \
        glds16(gB_ + soff,        (DST) + soff);                           \
        glds16(gB_ + 4096 + soff, (DST) + 4096 + soff);                    \
    } while (0)

    // prologue: stage B slab 0 of first chunk into buf0
    STAGE_B((size_t)split * 16, (char*)smem);

    int iter = 0;
    for (int chunk = split; chunk < nChunks; chunk += NS, ++iter) {
        f32x4 acc[4][4];   // acc[bi][zi]: bank-col frag bi x z-row frag zi
        #pragma unroll
        for (int bi = 0; bi < 4; ++bi)
            #pragma unroll
            for (int zi = 0; zi < 4; ++zi) acc[bi][zi] = (f32x4){0.f, 0.f, 0.f, 0.f};
        f32x4 rbv[4];      // rbv[bi][rr]: col-norm recip for this lane's 16 cols

        #pragma unroll 2
        for (int ks = 0; ks < 16; ++ks) {
            // buf[ks&1] fully staged once all waves pass this barrier (each drained its own
            // glds via vmcnt(0); those loads were issued a full iteration ago).
            KBAR();

            // A fragments straight from global (L2-hot 1MB tile) — issue first, longest
            // latency; compiler inserts the vmcnt wait right before the MFMA uses.
            const char* gA = (const char*)zh + (size_t)(rowblk * 16 + ks) * 8192;
            f16x8 af[4];
            #pragma unroll
            for (int zi = 0; zi < 4; ++zi)
                af[zi] = __builtin_bit_cast(f16x8,
                    *(const i32x4*)(gA + (wz * 4 + zi) * 1024 + quad * 256 + l16 * 16));

            if (ks < 15) {
                STAGE_B((size_t)chunk * 16 + ks + 1, (char*)smem + (((ks & 1) ^ 1) << 13));
            } else if (chunk + NS < nChunks) {
                // cross-chunk prefetch: B slab 0 of next chunk into buf0; lands during the
                // register-only epilogue, consumed at next chunk's ks=0 KBAR.
                STAGE_B((size_t)(chunk + NS) * 16, (char*)smem);
            }
            if (ks == 0) {
                // hoisted col-norm loads (lane-uniform across l16, consumed in epilogue)
                #pragma unroll
                for (int bi = 0; bi < 4; ++bi)
                    rbv[bi] = *(const f32x4*)(rb + chunk * 128 + wb * 64 + bi * 16 + quad * 4);
            }

            // swizzled B frag reads: group*1024 + quad*256 + l16*16 (conflict-free)
            const char* Bb = (const char*)smem + ((ks & 1) << 13);
            f16x8 bf[4];
            #pragma unroll
            for (int bi = 0; bi < 4; ++bi)
                bf[bi] = __builtin_bit_cast(f16x8,
                    *(const i32x4*)(Bb + (wb * 4 + bi) * 1024 + quad * 256 + l16 * 16));
            // swapped operands: out col(l16) = z-row, out row(quad*4+rr) = bank-col
            #pragma unroll
            for (int bi = 0; bi < 4; ++bi)
                #pragma unroll
                for (int zi = 0; zi < 4; ++zi)
                    acc[bi][zi] = __builtin_amdgcn_mfma_f32_16x16x32_f16(bf[bi], af[zi], acc[bi][zi], 0, 0, 0);
        }

        // epilogue: pure-register sorted-insert of this lane's 16 cols per z-row.
        // col = wb*64 + bi*16 + quad*4 + rr  (7 bits, no carry into iter field)
        const int tbase = (iter << 7) | (wb << 6) | (quad << 2);
        #pragma unroll
        for (int zi = 0; zi < 4; ++zi)
            #pragma unroll
            for (int bi = 0; bi < 4; ++bi)
                #pragma unroll
                for (int rr = 0; rr < 4; ++rr) {
                    float v = acc[bi][zi][rr] * rbv[bi][rr];
                    int kk = (__float_as_int(v) & KMASK) | (tbase + bi * 16 + rr);
                    int n1 = med3(kk, T[zi][0], T[zi][1]);
                    int n2 = med3(kk, T[zi][1], T[zi][2]);
                    int n3 = med3(kk, T[zi][2], T[zi][3]);
                    T[zi][0] = imax(kk, T[zi][0]);
                    T[zi][1] = n1; T[zi][2] = n2; T[zi][3] = n3;
                }
    }
    #undef STAGE_B

    // final cross-quad merge: lanes {l16, l16+16, l16+32, l16+48} hold disjoint col sets
    // for the same z-rows. Bitonic top-4 merge of sorted-desc lists via shfl_xor(16,32).
    #pragma unroll
    for (int zi = 0; zi < 4; ++zi) {
        int a0 = T[zi][0], a1 = T[zi][1], a2 = T[zi][2], a3 = T[zi][3];
        #pragma unroll
        for (int off = 16; off <= 32; off <<= 1) {
            int p0 = __shfl_xor(a0, off, 64);
            int p1 = __shfl_xor(a1, off, 64);
            int p2 = __shfl_xor(a2, off, 64);
            int p3 = __shfl_xor(a3, off, 64);
            int m0 = imax(a0, p3), m1 = imax(a1, p2), m2 = imax(a2, p1), m3 = imax(a3, p0);
            int b0 = imax(m0, m2), b2 = imin(m0, m2), b1 = imax(m1, m3), b3 = imin(m1, m3);
            a0 = imax(b0, b1); a1 = imin(b0, b1); a2 = imax(b2, b3); a3 = imin(b2, b3);
        }
        if (quad == 0) {
            i32x4 outk = { a0, a1, a2, a3 };
            const int row = rowblk * 128 + wz * 64 + zi * 16 + l16;
            *(i32x4*)(cand + (((size_t)row * NS + split) * 2 + wb) * 4) = outk;
        }
    }
}

// per row: pop exact top-32 of 768 packed keys, exact fp32 rescore, final top-5
__global__ __launch_bounds__(256) void merge_rescore_k(
    const int* __restrict__ cand,
    const float* __restrict__ z, const float* __restrict__ bank,
    const float* __restrict__ rz, const float* __restrict__ rb,
    const int* __restrict__ labels, float* __restrict__ out, int BK, int N) {

    __shared__ float zrow[DDIM];
    __shared__ int   idxs[32];
    __shared__ float dots[32];

    const int row = blockIdx.x;
    const int t = threadIdx.x, w = t >> 6, lane = t & 63;

    {   float2 v = *(const float2*)(z + (size_t)row * DDIM + t * 2);
        zrow[t * 2] = v.x; zrow[t * 2 + 1] = v.y; }

    if (w == 0) {
        int k[12];
        const int* cp = cand + (size_t)row * (NS * 2 * 4) + lane * 12;
        #pragma unroll
        for (int q = 0; q < 12; ++q) k[q] = cp[q];
        for (int r = 0; r < 32; ++r) {
            int lk = k[0], lq = 0;
            #pragma unroll
            for (int q = 1; q < 12; ++q) if (k[q] > lk) { lk = k[q]; lq = q; }
            int wk = lk, wl = lane, wq = lq;
            #pragma unroll
            for (int off = 32; off > 0; off >>= 1) {
                int ok = __shfl_xor(wk, off, 64);
                int ol = __shfl_xor(wl, off, 64);
                int oq = __shfl_xor(wq, off, 64);
                if (ok > wk || (ok == wk && ol < wl)) { wk = ok; wl = ol; wq = oq; }
            }
            if (lane == wl) {
                #pragma unroll
                for (int q = 0; q < 12; ++q) if (q == wq) k[q] = (int)0x80000000;
            }
            if (lane == 0) {
                int j = wl * 12 + wq;         // position -> (split, h, slot)
                int split = j >> 3;
                int c = wk & 127, it = (wk >> 7) & 15;
                int gi = (it * NS + split) * 128 + c;
                idxs[r] = gi < N ? gi : 0;    // statistically impossible, fault-guard only
            }
        }
    }
    __syncthreads();

    // exact fp32 raw dot for the 32 survivors: wave w handles w*8..w*8+7
    #pragma unroll
    for (int jj = 0; jj < 8; ++jj) {
        const int ci = idxs[w * 8 + jj];
        const float* br = bank + (size_t)ci * DDIM + lane * 8;
        float4 x0 = *(const float4*)br;
        float4 x1 = *(const float4*)(br + 4);
        const float* zz = zrow + lane * 8;
        float4 z0 = *(const float4*)zz;
        float4 z1 = *(const float4*)(zz + 4);
        float s = x0.x*z0.x + x0.y*z0.y + x0.z*z0.z + x0.w*z0.w
                + x1.x*z1.x + x1.y*z1.y + x1.z*z1.z + x1.w*z1.w;
        #pragma unroll
        for (int off = 32; off > 0; off >>= 1) s += __shfl_xor(s, off, 64);
        if (lane == 0) dots[w * 8 + jj] = s;
    }
    __syncthreads();

    if (w == 0) {
        const float rzv = rz[row];
        float v; int ii;
        if (lane < 32) { ii = idxs[lane]; v = dots[lane] * rzv * rb[ii]; }
        else           { ii = IMAX;       v = NEG_INF; }
        for (int r = 0; r < 5; ++r) {
            float bv = v; int bi = ii;
            #pragma unroll
            for (int off = 32; off > 0; off >>= 1) {
                float ov = __shfl_xor(bv, off, 64);
                int   oi = __shfl_xor(bi, off, 64);
                if (ov > bv || (ov == bv && oi < bi)) { bv = ov; bi = oi; }
            }
            if (v == bv && ii == bi) { v = NEG_INF; ii = IMAX; }
            if (lane == 0) {
                out[(size_t)row * 5 + r]          = (float)bi;
                out[BK + (size_t)row * 5 + r]     = bv;
                out[2 * BK + (size_t)row * 5 + r] = (float)labels[bi];
            }
        }
    }
}

extern "C" void kernel_launch(void* const* d_in, const int* in_sizes, int n_in,
                              void* d_out, int out_size, void* d_ws, size_t ws_size,
                              hipStream_t stream) {
    const float* z    = (const float*)d_in[0];
    const float* bank = (const float*)d_in[1];
    const int*   lab  = (const int*)d_in[2];
    const int B = in_sizes[0] / DDIM;     // 1024
    const int N = in_sizes[1] / DDIM;     // 100000
    const int BK = out_size / 3;          // 5120
    const int nChunks = (N + 127) >> 7;   // 782
    float* out = (float*)d_out;
    char* ws = (char*)d_ws;

    const size_t o_rz = 0;                                       // B floats (pad 4K)
    const size_t o_rb = 4096;                                    // nChunks*128 floats
    const size_t o_zh = o_rb + (size_t)nChunks * 128 * 4;        // z f16 tile (1 MB)
    const size_t o_bh = o_zh + (size_t)(B / 128) * 16 * 8192;    // bank f16 tile (102.5 MB)
    const size_t o_cv = o_bh + (size_t)nChunks * 16 * 8192;      // cand keys (3 MB)

    float* rz = (float*)(ws + o_rz);
    float* rb = (float*)(ws + o_rb);
    unsigned* zh = (unsigned*)(ws + o_zh);
    unsigned* bh = (unsigned*)(ws + o_bh);
    int* cand = (int*)(ws + o_cv);

    split_tile_k<<<nChunks + B / 128, 256, 0, stream>>>(z, bank, zh, bh, rz, rb, B, N, nChunks);
    gemm_screen_k<<<dim3(NS, B / 128), 256, 0, stream>>>(zh, bh, rb, cand, N, nChunks);
    merge_rescore_k<<<B, 256, 0, stream>>>(cand, z, bank, rz, rb, lab, out, BK, N);
}